// Round 15
// baseline (71.787 us; speedup 1.0000x reference)
//
#include <hip/hip_runtime.h>

typedef __attribute__((ext_vector_type(8))) short bf16x8;
typedef __attribute__((ext_vector_type(4))) float f32x4;

#define MFMA(a, b, c) __builtin_amdgcn_mfma_f32_16x16x32_bf16((a), (b), (c), 0, 0, 0)
#define LOG2E 1.4426950408889634f

__device__ __forceinline__ unsigned short f2bf(float f) {
    union { float f; unsigned u; } v; v.f = f;
    unsigned r = v.u + 0x7FFFu + ((v.u >> 16) & 1u);
    return (unsigned short)(r >> 16);
}
__device__ __forceinline__ float bf2f(unsigned short h) {
    union { unsigned u; float f; } v; v.u = ((unsigned)h) << 16;
    return v.f;
}
__device__ __forceinline__ float exp2fast(float x) {
#if __has_builtin(__builtin_amdgcn_exp2f)
    return __builtin_amdgcn_exp2f(x);
#else
    float r; asm("v_exp_f32 %0, %1" : "=v"(r) : "v"(x)); return r;
#endif
}
// 3-input max -> v_max3_f32 (clang fuses nested fmaxf)
__device__ __forceinline__ float fm3(float a, float b, float c) {
    return fmaxf(fmaxf(a, b), c);
}
// async global->LDS, 16B per lane, dest = ldsbase + lane*16 (wave-uniform base)
__device__ __forceinline__ void gload16(const void* g, void* l) {
    __builtin_amdgcn_global_load_lds(
        (const __attribute__((address_space(1))) void*)g,
        (__attribute__((address_space(3))) void*)l, 16, 0, 0);
}

// ---------------------------------------------------------------------------
// Workspace layout (bytes). ATT reuses the X region.
// ---------------------------------------------------------------------------
#define WS_QHI   0
#define WS_QLO   6291456
#define WS_KHI   12582912
#define WS_KLO   18874368
#define WS_VTHI  25165824
#define WS_RELH  37748736
#define WS_RELW  40894464
#define WS_WTH   44040192
#define WS_WTL   44924928
#define WS_PWTH  45809664
#define WS_PWTL  46104576
#define WS_XHI   46399488
#define WS_XLO   52690944
// end 58982400 bytes (56.25 MB)

// ---------------------------------------------------------------------------
// Fused prep: blocks [0,3072) split x -> bf16 hi (packed uint2 stores);
// [3072,3180) transpose qkv_w; [3180,3216) transpose proj_w (hi only).
// ---------------------------------------------------------------------------
__global__ __launch_bounds__(256) void prep_fused(const float* __restrict__ x,
        const float* __restrict__ qkv_w, const float* __restrict__ proj_w,
        unsigned short* __restrict__ xh,
        unsigned short* __restrict__ wth, unsigned short* __restrict__ pwth) {
    __shared__ float tile[64][65];
    const int bid = blockIdx.x;
    const int t = threadIdx.x;
    if (bid < 3072) {
        int i = bid * 256 + t;
        float4 v = ((const float4*)x)[i];
        uint2 o;
        o.x = (unsigned)f2bf(v.x) | ((unsigned)f2bf(v.y) << 16);
        o.y = (unsigned)f2bf(v.z) | ((unsigned)f2bf(v.w) << 16);
        *(uint2*)&xh[i * 4] = o;
        return;
    }
    const float* w; unsigned short *oh; int K, N, bx, by;
    if (bid < 3180) {
        int b2 = bid - 3072;
        w = qkv_w; oh = wth; K = 384; N = 1152;
        bx = b2 % 18; by = b2 / 18;
    } else {
        int b3 = bid - 3180;
        w = proj_w; oh = pwth; K = 384; N = 384;
        bx = b3 % 6; by = b3 / 6;
    }
    const int k0 = by * 64, n0 = bx * 64;
#pragma unroll
    for (int i = 0; i < 16; ++i) {
        int idx = t + i * 256;
        int r = idx >> 6, c = idx & 63;
        tile[r][c] = w[(size_t)(k0 + r) * N + n0 + c];
    }
    __syncthreads();
#pragma unroll
    for (int i = 0; i < 16; ++i) {
        int idx = t + i * 256;
        int r = idx >> 6, c = idx & 63;    // r = n-local, c = k-local
        oh[(size_t)(n0 + r) * K + k0 + c] = f2bf(tile[c][r]);
    }
}

// ---------------------------------------------------------------------------
// QKV GEMM: [8192,384] @ [384,1152] + bias. 64x64 tile, BK=64, chunked XCD
// swizzle (2304 = 8 x 288). Pure bf16-hi MFMA. A dbuf (1-deep) + B 3-ring
// (2-deep prefetch). LDS 40KB -> 4 blocks/CU. In-order vmcnt schedule:
// prologue A0,B0,B1; iter kb issues A(kb+1), B(kb+2); steady vmcnt(6)
// retires exactly A(kb),B(kb); kb=4 -> vmcnt(4); kb=5 -> vmcnt(0).
// Epilogue: q hi (x SCALE*log2e), k hi, v^T hi (packed uint2 stores).
// ---------------------------------------------------------------------------
__global__ __launch_bounds__(256) void qkv_gemm_mfma(
        const unsigned short* __restrict__ xh,
        const unsigned short* __restrict__ wth,
        const float* __restrict__ bias,
        unsigned short* __restrict__ qh,
        unsigned short* __restrict__ kh,
        unsigned short* __restrict__ vth) {
    __shared__ unsigned short Ah[2][4096], Bh[3][4096];
    const int t = threadIdx.x;
    const int lane = t & 63, wid = t >> 6;
    const int C = lane & 15, G = lane >> 4;
    const int nbid = (blockIdx.x & 7) * 288 + (blockIdx.x >> 3);
    const int row0 = (nbid / 18) * 64, col0 = (nbid % 18) * 64;
    const int rl = wid * 16 + (lane >> 3);
    const int cbyt = ((lane & 7) << 4) ^ ((lane >> 3) << 4);
    const char* pAh = (const char*)xh + (size_t)(row0 + rl) * 768 + cbyt;
    const char* pBh = (const char*)wth + (size_t)(col0 + rl) * 768 + cbyt;
    const int dof = wid * 2048;
    // prologue: A0, B0, B1 (issue order matters for vmcnt schedule)
    gload16(pAh, (char*)Ah[0] + dof); gload16(pAh + 6144, (char*)Ah[0] + dof + 1024);
    gload16(pBh, (char*)Bh[0] + dof); gload16(pBh + 6144, (char*)Bh[0] + dof + 1024);
    gload16(pBh + 128, (char*)Bh[1] + dof); gload16(pBh + 128 + 6144, (char*)Bh[1] + dof + 1024);
    int cur = 0;
    f32x4 acc[4] = {};
    for (int kb = 0; kb < 6; ++kb) {
        if (kb < 5) {    // A(kb+1) -> Ah[cur^1]
            const int o = (kb + 1) * 128;
            gload16(pAh + o, (char*)Ah[cur^1] + dof);
            gload16(pAh + o + 6144, (char*)Ah[cur^1] + dof + 1024);
        }
        if (kb < 4) {    // B(kb+2) -> Bh[(kb+2)%3]
            const int o = (kb + 2) * 128;
            char* dB = (char*)Bh[(kb + 2) % 3] + dof;
            gload16(pBh + o, dB); gload16(pBh + o + 6144, dB + 1024);
        }
        __builtin_amdgcn_sched_barrier(0);
        if (kb < 4)      { asm volatile("s_waitcnt vmcnt(6)" ::: "memory"); }
        else if (kb < 5) { asm volatile("s_waitcnt vmcnt(4)" ::: "memory"); }
        else             { asm volatile("s_waitcnt vmcnt(0)" ::: "memory"); }
        __builtin_amdgcn_s_barrier();
        __builtin_amdgcn_sched_barrier(0);
        const unsigned short* AhB = Ah[cur];
        const unsigned short* BhB = Bh[kb % 3];
#pragma unroll
        for (int ks = 0; ks < 2; ++ks) {
            int arow = wid * 16 + C;
            int aoff = arow * 128 + ((ks * 64 + G * 16) ^ ((arow & 7) << 4));
            bf16x8 ah = *(const bf16x8*)((char*)AhB + aoff);
#pragma unroll
            for (int s = 0; s < 4; ++s) {
                int brow = s * 16 + C;
                int boff = brow * 128 + ((ks * 64 + G * 16) ^ ((brow & 7) << 4));
                bf16x8 bh = *(const bf16x8*)((char*)BhB + boff);
                acc[s] = MFMA(ah, bh, acc[s]);
            }
        }
        __builtin_amdgcn_s_barrier();   // bare: protect buffer reuse next iter
        cur ^= 1;
    }
#pragma unroll
    for (int s = 0; s < 4; ++s) {
        int n = col0 + s * 16 + C;
        float bv = bias[n];
        int tsel = n / 384;
        int rem = n - tsel * 384;
        int head = rem >> 6, d = rem & 63;
        int m0 = row0 + wid * 16 + 4 * G;
        int b = m0 >> 10, hw0 = m0 & 1023;
        int g = b * 6 + head;
        if (tsel == 2) {
            unsigned short hv[4];
#pragma unroll
            for (int r = 0; r < 4; ++r) hv[r] = f2bf(acc[s][r] + bv);
            uint2 pv;
            pv.x = (unsigned)hv[0] | ((unsigned)hv[1] << 16);
            pv.y = (unsigned)hv[2] | ((unsigned)hv[3] << 16);
            *(uint2*)&vth[((size_t)g * 64 + d) * 1024 + hw0] = pv;
        } else {
#pragma unroll
            for (int r = 0; r < 4; ++r) {
                float val = acc[s][r] + bv;
                if (tsel == 0) val *= 0.125f * LOG2E;   // SCALE*log2e: exp2 domain
                size_t o = ((size_t)g * 1024 + hw0 + r) * 64 + d;
                if (tsel == 0) qh[o] = f2bf(val);
                else           kh[o] = f2bf(val);
            }
        }
    }
}

// ---------------------------------------------------------------------------
// rel_h / rel_w via MFMA. q is pre-scaled by SCALE*log2e -> x8 yields
// log2e-scaled rel (consistent exp2 domain).
// ---------------------------------------------------------------------------
__global__ __launch_bounds__(256) void rel_mfma(
        const unsigned short* __restrict__ qh,
        const float* __restrict__ rph, const float* __restrict__ rpw,
        unsigned short* __restrict__ relh, unsigned short* __restrict__ relw) {
    __shared__ unsigned short Bs[32 * 64];
    const int t = threadIdx.x;
    const int lane = t & 63, wid = t >> 6;
    const int C = lane & 15, G = lane >> 4;
    const int pos = blockIdx.x;
    const int g0 = blockIdx.y * 8;
    const int mode = blockIdx.z;
    const float* rp = (mode == 0) ? rph : rpw;
    {   // stage B[k][d] = bf16(rp[pos+31-k][d]), XOR-swizzled 128B rows
        int k = t >> 3, d8 = t & 7;
        const float* src = rp + (size_t)(pos + 31 - k) * 64 + d8 * 8;
        float4 f0 = *(const float4*)src;
        float4 f1 = *(const float4*)(src + 4);
        unsigned short hv[8] = { f2bf(f0.x), f2bf(f0.y), f2bf(f0.z), f2bf(f0.w),
                                 f2bf(f1.x), f2bf(f1.y), f2bf(f1.z), f2bf(f1.w) };
        int bo = k * 128 + ((d8 * 16) ^ ((k & 7) << 4));
        *(bf16x8*)((char*)Bs + bo) = *(bf16x8*)hv;
    }
    __syncthreads();
    bf16x8 bf[2][2];
#pragma unroll
    for (int s = 0; s < 2; ++s)
#pragma unroll
        for (int ks = 0; ks < 2; ++ks) {
            int row = s * 16 + C;
            int off = row * 128 + ((ks * 64 + G * 16) ^ ((row & 7) << 4));
            bf[s][ks] = *(const bf16x8*)((char*)Bs + off);
        }
#pragma unroll
    for (int ib = 0; ib < 4; ++ib) {
        int arow = ib * 64 + wid * 16 + C;
        int gi = arow >> 5, w = arow & 31;
        int hw = (mode == 0) ? (pos * 32 + w) : (w * 32 + pos);
        const unsigned short* qrow = qh + ((size_t)(g0 + gi) * 1024 + hw) * 64;
        bf16x8 a0 = *(const bf16x8*)(qrow + G * 8);
        bf16x8 a1 = *(const bf16x8*)(qrow + 32 + G * 8);
        f32x4 acc[2] = {};
#pragma unroll
        for (int s = 0; s < 2; ++s) {
            acc[s] = MFMA(a0, bf[s][0], acc[s]);
            acc[s] = MFMA(a1, bf[s][1], acc[s]);
        }
        unsigned short* dst = (mode == 0) ? relh : relw;
#pragma unroll
        for (int s = 0; s < 2; ++s)
#pragma unroll
            for (int rr = 0; rr < 4; ++rr) {
                int orow = ib * 64 + wid * 16 + 4 * G + rr;
                int ogi = orow >> 5, ow = orow & 31;
                int ohw = (mode == 0) ? (pos * 32 + ow) : (ow * 32 + pos);
                dst[((size_t)(g0 + ogi) * 1024 + ohw) * 32 + s * 16 + C] =
                    f2bf(acc[s][rr] * 8.0f);
            }
    }
}

// ---------------------------------------------------------------------------
// Flash attention, 4 waves x 16 q-rows + K-path 2-deep prefetch (Kh 3-ring,
// Vh dbuf). LDS 52.4KB -> 3 blocks/CU. In-order vmcnt schedule: prologue
// K0,V0,K1; per iter issue V(kb+1), K(kb+2); steady vmcnt(6); kb=14 ->
// vmcnt(4); kb=15 -> vmcnt(0).
// ---------------------------------------------------------------------------
__global__ __launch_bounds__(256) void attn_mfma(
        const unsigned short* __restrict__ qh,
        const unsigned short* __restrict__ kh_g,
        const unsigned short* __restrict__ vth_g,
        const unsigned short* __restrict__ relh, const unsigned short* __restrict__ relw,
        unsigned short* __restrict__ atth) {
    __shared__ unsigned short Kh[3][4096], Vh[2][4096];
    __shared__ unsigned short Pl[4][1024];
    __shared__ unsigned short RelU[4][16 * 34];
    const int t = threadIdx.x;
    const int lane = t & 63, wid = t >> 6;
    const int C = lane & 15, G = lane >> 4;
    // XCD-aware swizzle: 768 blocks, 96 per XCD -> each XCD owns 6 whole heads
    const int bid = blockIdx.x;
    const int wgid = (bid & 7) * 96 + (bid >> 3);
    const int g = wgid >> 4, qb = wgid & 15;
    const int qtile = qb * 64 + wid * 16;

    // ---- stage rel_h rows (64 x 32 bf16) into per-wave LDS ----
    {
        const unsigned short* src = relh + ((size_t)g * 1024 + qb * 64) * 32;
#pragma unroll
        for (int j = 0; j < 8; ++j) {
            int i = t + j * 256;
            int row = i >> 5, col = i & 31;
            RelU[row >> 4][(row & 15) * 34 + col] = src[i];
        }
    }
    // ---- staging source addresses (per-lane, pre-swizzled) ----
    const int cbyt = ((lane & 7) << 4) ^ ((lane >> 3) << 4);
    const char* khbase = (const char*)(kh_g + (size_t)g * 65536)
                         + (wid * 16 + (lane >> 3)) * 128 + cbyt;
    const char* vhbase = (const char*)(vth_g + (size_t)g * 65536)
                         + (wid * 16 + (lane >> 3)) * 2048 + cbyt;
    // ---- Q fragments (hoisted, hi only) ----
    bf16x8 qfh[2];
    {
        size_t qo = ((size_t)g * 1024 + qtile + C) * 64;
        qfh[0] = *(const bf16x8*)(qh + qo + G * 8);
        qfh[1] = *(const bf16x8*)(qh + qo + 32 + G * 8);
    }
    // ---- rel_w hoisted: rw8[e][r] = relw[q=qtile+C][e*16 + 4G + r] ----
    float rw8[2][4];
    {
        const unsigned short* rwp = relw + ((size_t)g * 1024 + qtile + C) * 32;
#pragma unroll
        for (int e = 0; e < 2; ++e)
#pragma unroll
            for (int r = 0; r < 4; ++r)
                rw8[e][r] = bf2f(rwp[e * 16 + 4 * G + r]);
    }
    f32x4 O[4] = {};
    float m_ = -1e30f, l_ = 0.f;
    unsigned short* Pw = Pl[wid];

    __syncthreads();   // rel writes visible; drains all prologue vmem
    // ---- prologue: K0, V0, K1 (issue order matters for vmcnt schedule) ----
    {
        char* dK0 = (char*)Kh[0] + wid * 2048;
        char* dV0 = (char*)Vh[0] + wid * 2048;
        char* dK1 = (char*)Kh[1] + wid * 2048;
        gload16(khbase, dK0);          gload16(khbase + 1024, dK0 + 1024);
        gload16(vhbase, dV0);          gload16(vhbase + 16384, dV0 + 1024);
        gload16(khbase + 8192, dK1);   gload16(khbase + 9216, dK1 + 1024);
    }

    for (int kb = 0; kb < 16; ++kb) {
        if (kb < 15) {   // V[kb+1] -> Vh[(kb+1)&1]
            const char* sV = vhbase + (kb + 1) * 128;
            char* dV = (char*)Vh[(kb + 1) & 1] + wid * 2048;
            gload16(sV, dV); gload16(sV + 16384, dV + 1024);
        }
        if (kb < 14) {   // K[kb+2] -> Kh[(kb+2)%3]
            const char* sK = khbase + (kb + 2) * 8192;
            char* dK = (char*)Kh[(kb + 2) % 3] + wid * 2048;
            gload16(sK, dK); gload16(sK + 1024, dK + 1024);
        }
        __builtin_amdgcn_sched_barrier(0);
        if (kb < 14)      { asm volatile("s_waitcnt vmcnt(6)" ::: "memory"); }
        else if (kb < 15) { asm volatile("s_waitcnt vmcnt(4)" ::: "memory"); }
        else              { asm volatile("s_waitcnt vmcnt(0)" ::: "memory"); }
        __builtin_amdgcn_s_barrier();
        __builtin_amdgcn_sched_barrier(0);
        const unsigned short* khbuf = Kh[kb % 3];
        const unsigned short* vhbuf = Vh[kb & 1];
        // ---- QK^T swapped, hi-only: S[s][r] = score(q=qtile+C, k=16s+4G+r) ----
        f32x4 S[4] = {};
        __builtin_amdgcn_s_setprio(1);
#pragma unroll
        for (int ks = 0; ks < 2; ++ks) {
#pragma unroll
            for (int s = 0; s < 4; ++s) {
                int row = s * 16 + C;
                int off = row * 128 + ((ks * 64 + G * 16) ^ ((row & 7) << 4));
                bf16x8 bh = *(const bf16x8*)((char*)khbuf + off);
                S[s] = MFMA(bh, qfh[ks], S[s]);
            }
        }
        __builtin_amdgcn_s_setprio(0);
        // ---- rel terms: rh from LDS (1 dword), rw hoisted ----
        {
            unsigned rp = *(const unsigned*)((const char*)&RelU[wid][0]
                                             + C * 68 + 4 * kb);
            float rh0 = bf2f((unsigned short)(rp & 0xFFFF));
            float rh1 = bf2f((unsigned short)(rp >> 16));
#pragma unroll
            for (int s = 0; s < 4; ++s) {
                float rh = (s < 2) ? rh0 : rh1;
#pragma unroll
                for (int r = 0; r < 4; ++r)
                    S[s][r] += rh + rw8[s & 1][r];
            }
        }
        // ---- online softmax (scalar state, exp2 domain, defer-max) ----
        float mt = fm3(fm3(fm3(S[0][0], S[0][1], S[0][2]),
                           fm3(S[0][3], S[1][0], S[1][1]),
                           fm3(S[1][2], S[1][3], S[2][0])),
                       fm3(S[2][1], S[2][2], S[2][3]),
                       fm3(S[3][0], S[3][1], S[3][2]));
        mt = fmaxf(mt, S[3][3]);
        mt = fmaxf(mt, __shfl_xor(mt, 16));
        mt = fmaxf(mt, __shfl_xor(mt, 32));
        if (__any(mt - m_ > 11.f)) {
            float mn = fmaxf(m_, mt);
            float corr = exp2fast(m_ - mn);
            m_ = mn;
            l_ *= corr;
            float cO[4];
#pragma unroll
            for (int r = 0; r < 4; ++r) cO[r] = __shfl(corr, 4 * G + r);
#pragma unroll
            for (int s = 0; s < 4; ++s)
#pragma unroll
                for (int r = 0; r < 4; ++r) O[s][r] *= cO[r];
        }
        float lt = 0.f;
#pragma unroll
        for (int s = 0; s < 4; ++s)
#pragma unroll
            for (int r = 0; r < 4; ++r) {
                S[s][r] = exp2fast(S[s][r] - m_);
                lt += S[s][r];
            }
        l_ += lt;
        // ---- P pack: cvt_pk pairs (k consecutive) + ds_write_b64 ----
#pragma unroll
        for (int s = 0; s < 4; ++s) {
            unsigned d0, d1;
            asm("v_cvt_pk_bf16_f32 %0, %1, %2" : "=v"(d0) : "v"(S[s][0]), "v"(S[s][1]));
            asm("v_cvt_pk_bf16_f32 %0, %1, %2" : "=v"(d1) : "v"(S[s][2]), "v"(S[s][3]));
            int bo = C * 128 + (((s * 16 + 4 * G) * 2) ^ ((C & 7) << 4));
            uint2 dv; dv.x = d0; dv.y = d1;
            *(uint2*)((char*)Pw + bo) = dv;
        }
        // ---- PV (V hi only) ----
        __builtin_amdgcn_s_setprio(1);
#pragma unroll
        for (int ks = 0; ks < 2; ++ks) {
            int aoff = C * 128 + ((ks * 64 + G * 16) ^ ((C & 7) << 4));
            bf16x8 pa = *(const bf16x8*)((char*)Pw + aoff);
#pragma unroll
            for (int s = 0; s < 4; ++s) {
                int vrow = s * 16 + C;
                int voff = vrow * 128 + ((ks * 64 + G * 16) ^ ((vrow & 7) << 4));
                bf16x8 vh = *(const bf16x8*)((char*)vhbuf + voff);
                O[s] = MFMA(pa, vh, O[s]);
            }
        }
        __builtin_amdgcn_s_setprio(0);
        __builtin_amdgcn_s_barrier();   // bare: fence buffer reuse (no drain)
    }
    // ---- epilogue: reduce l across G, transpose to O layout, write hi ----
    l_ += __shfl_xor(l_, 16);
    l_ += __shfl_xor(l_, 32);
    const int b = g / 6, head = g - b * 6;
#pragma unroll
    for (int r = 0; r < 4; ++r) {
        float inv = 1.0f / __shfl(l_, 4 * G + r);
        int token = qtile + 4 * G + r;
        size_t ob = ((size_t)b * 1024 + token) * 384 + head * 64;
#pragma unroll
        for (int s = 0; s < 4; ++s)
            atth[ob + s * 16 + C] = f2bf(O[s][r] * inv);
    }
}

// ---------------------------------------------------------------------------
// Output projection: [8192,384] @ [384,384] + bias -> fp32 out. Hi-only,
// A dbuf + B 3-ring (2-deep), chunked XCD swizzle. LDS 40KB -> 4 blocks/CU.
// Same vmcnt schedule as qkv.
// ---------------------------------------------------------------------------
__global__ __launch_bounds__(256) void proj_gemm_mfma(
        const unsigned short* __restrict__ ah_g,
        const unsigned short* __restrict__ bth,
        const float* __restrict__ bias, float* __restrict__ out) {
    __shared__ unsigned short Ah[2][4096], Bh[3][4096];
    const int t = threadIdx.x;
    const int lane = t & 63, wid = t >> 6;
    const int C = lane & 15, G = lane >> 4;
    const int nbid = (blockIdx.x & 7) * 96 + (blockIdx.x >> 3);
    const int row0 = (nbid / 6) * 64, col0 = (nbid % 6) * 64;
    const int rl = wid * 16 + (lane >> 3);
    const int cbyt = ((lane & 7) << 4) ^ ((lane >> 3) << 4);
    const char* pAh = (const char*)ah_g + (size_t)(row0 + rl) * 768 + cbyt;
    const char* pBh = (const char*)bth + (size_t)(col0 + rl) * 768 + cbyt;
    const int dof = wid * 2048;
    gload16(pAh, (char*)Ah[0] + dof); gload16(pAh + 6144, (char*)Ah[0] + dof + 1024);
    gload16(pBh, (char*)Bh[0] + dof); gload16(pBh + 6144, (char*)Bh[0] + dof + 1024);
    gload16(pBh + 128, (char*)Bh[1] + dof); gload16(pBh + 128 + 6144, (char*)Bh[1] + dof + 1024);
    int cur = 0;
    f32x4 acc[4] = {};
    for (int kb = 0; kb < 6; ++kb) {
        if (kb < 5) {
            const int o = (kb + 1) * 128;
            gload16(pAh + o, (char*)Ah[cur^1] + dof);
            gload16(pAh + o + 6144, (char*)Ah[cur^1] + dof + 1024);
        }
        if (kb < 4) {
            const int o = (kb + 2) * 128;
            char* dB = (char*)Bh[(kb + 2) % 3] + dof;
            gload16(pBh + o, dB); gload16(pBh + o + 6144, dB + 1024);
        }
        __builtin_amdgcn_sched_barrier(0);
        if (kb < 4)      { asm volatile("s_waitcnt vmcnt(6)" ::: "memory"); }
        else if (kb < 5) { asm volatile("s_waitcnt vmcnt(4)" ::: "memory"); }
        else             { asm volatile("s_waitcnt vmcnt(0)" ::: "memory"); }
        __builtin_amdgcn_s_barrier();
        __builtin_amdgcn_sched_barrier(0);
        const unsigned short* AhB = Ah[cur];
        const unsigned short* BhB = Bh[kb % 3];
#pragma unroll
        for (int ks = 0; ks < 2; ++ks) {
            int arow = wid * 16 + C;
            int aoff = arow * 128 + ((ks * 64 + G * 16) ^ ((arow & 7) << 4));
            bf16x8 ah = *(const bf16x8*)((char*)AhB + aoff);
#pragma unroll
            for (int s = 0; s < 4; ++s) {
                int brow = s * 16 + C;
                int boff = brow * 128 + ((ks * 64 + G * 16) ^ ((brow & 7) << 4));
                bf16x8 bh = *(const bf16x8*)((char*)BhB + boff);
                acc[s] = MFMA(ah, bh, acc[s]);
            }
        }
        __builtin_amdgcn_s_barrier();
        cur ^= 1;
    }
#pragma unroll
    for (int s = 0; s < 4; ++s) {
        int n = col0 + s * 16 + C;
        float bv = bias[n];
#pragma unroll
        for (int r = 0; r < 4; ++r) {
            int m = row0 + wid * 16 + 4 * G + r;
            out[(size_t)m * 384 + n] = acc[s][r] + bv;
        }
    }
}

extern "C" void kernel_launch(void* const* d_in, const int* in_sizes, int n_in,
                              void* d_out, int out_size, void* d_ws, size_t ws_size,
                              hipStream_t stream) {
    const float* x      = (const float*)d_in[0];
    const float* qkv_w  = (const float*)d_in[1];
    const float* qkv_b  = (const float*)d_in[2];
    const float* proj_w = (const float*)d_in[3];
    const float* proj_b = (const float*)d_in[4];
    const float* rph    = (const float*)d_in[5];
    const float* rpw    = (const float*)d_in[6];
    char* ws = (char*)d_ws;

    unsigned short* QHI  = (unsigned short*)(ws + WS_QHI);
    unsigned short* KHI  = (unsigned short*)(ws + WS_KHI);
    unsigned short* VTHI = (unsigned short*)(ws + WS_VTHI);
    unsigned short* RELH = (unsigned short*)(ws + WS_RELH);
    unsigned short* RELW = (unsigned short*)(ws + WS_RELW);
    unsigned short* WTH  = (unsigned short*)(ws + WS_WTH);
    unsigned short* PWTH = (unsigned short*)(ws + WS_PWTH);
    unsigned short* XHI  = (unsigned short*)(ws + WS_XHI);
    unsigned short* ATTH = XHI;   // reuse (x consumed before attn writes)

    prep_fused<<<3216, 256, 0, stream>>>(x, qkv_w, proj_w, XHI, WTH, PWTH);
    qkv_gemm_mfma<<<2304, 256, 0, stream>>>(XHI, WTH, qkv_b, QHI, KHI, VTHI);
    rel_mfma<<<dim3(32, 6, 2), 256, 0, stream>>>(QHI, rph, rpw, RELH, RELW);
    attn_mfma<<<768, 256, 0, stream>>>(QHI, KHI, VTHI, RELH, RELW, ATTH);
    proj_gemm_mfma<<<768, 256, 0, stream>>>(ATTH, PWTH, proj_b, (float*)d_out);
}

// Round 17
// 71.440 us; speedup vs baseline: 1.0048x; 1.0048x over previous
//
#include <hip/hip_runtime.h>

typedef __attribute__((ext_vector_type(8))) short bf16x8;
typedef __attribute__((ext_vector_type(4))) float f32x4;

#define MFMA(a, b, c) __builtin_amdgcn_mfma_f32_16x16x32_bf16((a), (b), (c), 0, 0, 0)
#define LOG2E 1.4426950408889634f

__device__ __forceinline__ unsigned short f2bf(float f) {
    union { float f; unsigned u; } v; v.f = f;
    unsigned r = v.u + 0x7FFFu + ((v.u >> 16) & 1u);
    return (unsigned short)(r >> 16);
}
__device__ __forceinline__ float bf2f(unsigned short h) {
    union { unsigned u; float f; } v; v.u = ((unsigned)h) << 16;
    return v.f;
}
__device__ __forceinline__ float exp2fast(float x) {
#if __has_builtin(__builtin_amdgcn_exp2f)
    return __builtin_amdgcn_exp2f(x);
#else
    float r; asm("v_exp_f32 %0, %1" : "=v"(r) : "v"(x)); return r;
#endif
}
// 3-input max -> v_max3_f32 (clang fuses nested fmaxf)
__device__ __forceinline__ float fm3(float a, float b, float c) {
    return fmaxf(fmaxf(a, b), c);
}
// async global->LDS, 16B per lane, dest = ldsbase + lane*16 (wave-uniform base)
__device__ __forceinline__ void gload16(const void* g, void* l) {
    __builtin_amdgcn_global_load_lds(
        (const __attribute__((address_space(1))) void*)g,
        (__attribute__((address_space(3))) void*)l, 16, 0, 0);
}

// ---------------------------------------------------------------------------
// Workspace layout (bytes). ATT reuses the X region.
// ---------------------------------------------------------------------------
#define WS_QHI   0
#define WS_QLO   6291456
#define WS_KHI   12582912
#define WS_KLO   18874368
#define WS_VTHI  25165824
#define WS_RELH  37748736
#define WS_RELW  40894464
#define WS_WTH   44040192
#define WS_WTL   44924928
#define WS_PWTH  45809664
#define WS_PWTL  46104576
#define WS_XHI   46399488
#define WS_XLO   52690944
// end 58982400 bytes (56.25 MB)

// ---------------------------------------------------------------------------
// Fused prep: blocks [0,3072) split x -> bf16 hi (packed uint2 stores);
// [3072,3180) transpose qkv_w; [3180,3216) transpose proj_w (hi only).
// ---------------------------------------------------------------------------
__global__ __launch_bounds__(256) void prep_fused(const float* __restrict__ x,
        const float* __restrict__ qkv_w, const float* __restrict__ proj_w,
        unsigned short* __restrict__ xh,
        unsigned short* __restrict__ wth, unsigned short* __restrict__ pwth) {
    __shared__ float tile[64][65];
    const int bid = blockIdx.x;
    const int t = threadIdx.x;
    if (bid < 3072) {
        int i = bid * 256 + t;
        float4 v = ((const float4*)x)[i];
        uint2 o;
        o.x = (unsigned)f2bf(v.x) | ((unsigned)f2bf(v.y) << 16);
        o.y = (unsigned)f2bf(v.z) | ((unsigned)f2bf(v.w) << 16);
        *(uint2*)&xh[i * 4] = o;
        return;
    }
    const float* w; unsigned short *oh; int K, N, bx, by;
    if (bid < 3180) {
        int b2 = bid - 3072;
        w = qkv_w; oh = wth; K = 384; N = 1152;
        bx = b2 % 18; by = b2 / 18;
    } else {
        int b3 = bid - 3180;
        w = proj_w; oh = pwth; K = 384; N = 384;
        bx = b3 % 6; by = b3 / 6;
    }
    const int k0 = by * 64, n0 = bx * 64;
#pragma unroll
    for (int i = 0; i < 16; ++i) {
        int idx = t + i * 256;
        int r = idx >> 6, c = idx & 63;
        tile[r][c] = w[(size_t)(k0 + r) * N + n0 + c];
    }
    __syncthreads();
#pragma unroll
    for (int i = 0; i < 16; ++i) {
        int idx = t + i * 256;
        int r = idx >> 6, c = idx & 63;    // r = n-local, c = k-local
        oh[(size_t)(n0 + r) * K + k0 + c] = f2bf(tile[c][r]);
    }
}

// ---------------------------------------------------------------------------
// QKV GEMM: [8192,384] @ [384,1152] + bias. 64x64 tile, BK=64, counted-vmcnt
// dbuf (single-class: ALL staging via global_load_lds), chunked XCD swizzle
// (2304 = 8 x 288). Pure bf16-hi MFMA. LDS 32KB -> 5 blocks/CU.
// Epilogue: q hi (x SCALE*log2e), k hi, v^T hi (packed uint2 stores).
// ---------------------------------------------------------------------------
__global__ __launch_bounds__(256) void qkv_gemm_mfma(
        const unsigned short* __restrict__ xh,
        const unsigned short* __restrict__ wth,
        const float* __restrict__ bias,
        unsigned short* __restrict__ qh,
        unsigned short* __restrict__ kh,
        unsigned short* __restrict__ vth) {
    __shared__ unsigned short Ah[2][4096], Bh[2][4096];
    const int t = threadIdx.x;
    const int lane = t & 63, wid = t >> 6;
    const int C = lane & 15, G = lane >> 4;
    const int nbid = (blockIdx.x & 7) * 288 + (blockIdx.x >> 3);
    const int row0 = (nbid / 18) * 64, col0 = (nbid % 18) * 64;
    const int rl = wid * 16 + (lane >> 3);
    const int cbyt = ((lane & 7) << 4) ^ ((lane >> 3) << 4);
    const char* pAh = (const char*)xh + (size_t)(row0 + rl) * 768 + cbyt;
    const char* pBh = (const char*)wth + (size_t)(col0 + rl) * 768 + cbyt;
    const int dof = wid * 2048;
    // prologue: stage tile 0 into buf 0 (4 loads)
    gload16(pAh, (char*)Ah[0] + dof); gload16(pAh + 6144, (char*)Ah[0] + dof + 1024);
    gload16(pBh, (char*)Bh[0] + dof); gload16(pBh + 6144, (char*)Bh[0] + dof + 1024);
    int cur = 0;
    f32x4 acc[4] = {};
    for (int kb = 0; kb < 6; ++kb) {
        if (kb < 5) {
            const int o = (kb + 1) * 128;
            gload16(pAh + o, (char*)Ah[cur^1] + dof); gload16(pAh + o + 6144, (char*)Ah[cur^1] + dof + 1024);
            gload16(pBh + o, (char*)Bh[cur^1] + dof); gload16(pBh + o + 6144, (char*)Bh[cur^1] + dof + 1024);
            __builtin_amdgcn_sched_barrier(0);
            asm volatile("s_waitcnt vmcnt(4)" ::: "memory");
        } else {
            asm volatile("s_waitcnt vmcnt(0)" ::: "memory");
        }
        __builtin_amdgcn_s_barrier();
        __builtin_amdgcn_sched_barrier(0);
        const unsigned short* AhB = Ah[cur];
        const unsigned short* BhB = Bh[cur];
#pragma unroll
        for (int ks = 0; ks < 2; ++ks) {
            int arow = wid * 16 + C;
            int aoff = arow * 128 + ((ks * 64 + G * 16) ^ ((arow & 7) << 4));
            bf16x8 ah = *(const bf16x8*)((char*)AhB + aoff);
#pragma unroll
            for (int s = 0; s < 4; ++s) {
                int brow = s * 16 + C;
                int boff = brow * 128 + ((ks * 64 + G * 16) ^ ((brow & 7) << 4));
                bf16x8 bh = *(const bf16x8*)((char*)BhB + boff);
                acc[s] = MFMA(ah, bh, acc[s]);
            }
        }
        __builtin_amdgcn_s_barrier();   // bare: protect buffer reuse next iter
        cur ^= 1;
    }
#pragma unroll
    for (int s = 0; s < 4; ++s) {
        int n = col0 + s * 16 + C;
        float bv = bias[n];
        int tsel = n / 384;
        int rem = n - tsel * 384;
        int head = rem >> 6, d = rem & 63;
        int m0 = row0 + wid * 16 + 4 * G;
        int b = m0 >> 10, hw0 = m0 & 1023;
        int g = b * 6 + head;
        if (tsel == 2) {
            unsigned short hv[4];
#pragma unroll
            for (int r = 0; r < 4; ++r) hv[r] = f2bf(acc[s][r] + bv);
            uint2 pv;
            pv.x = (unsigned)hv[0] | ((unsigned)hv[1] << 16);
            pv.y = (unsigned)hv[2] | ((unsigned)hv[3] << 16);
            *(uint2*)&vth[((size_t)g * 64 + d) * 1024 + hw0] = pv;
        } else {
#pragma unroll
            for (int r = 0; r < 4; ++r) {
                float val = acc[s][r] + bv;
                if (tsel == 0) val *= 0.125f * LOG2E;   // SCALE*log2e: exp2 domain
                size_t o = ((size_t)g * 1024 + hw0 + r) * 64 + d;
                if (tsel == 0) qh[o] = f2bf(val);
                else           kh[o] = f2bf(val);
            }
        }
    }
}

// ---------------------------------------------------------------------------
// rel_h / rel_w via MFMA. q is pre-scaled by SCALE*log2e -> x8 yields
// log2e-scaled rel (consistent exp2 domain).
// ---------------------------------------------------------------------------
__global__ __launch_bounds__(256) void rel_mfma(
        const unsigned short* __restrict__ qh,
        const float* __restrict__ rph, const float* __restrict__ rpw,
        unsigned short* __restrict__ relh, unsigned short* __restrict__ relw) {
    __shared__ unsigned short Bs[32 * 64];
    const int t = threadIdx.x;
    const int lane = t & 63, wid = t >> 6;
    const int C = lane & 15, G = lane >> 4;
    const int pos = blockIdx.x;
    const int g0 = blockIdx.y * 8;
    const int mode = blockIdx.z;
    const float* rp = (mode == 0) ? rph : rpw;
    {   // stage B[k][d] = bf16(rp[pos+31-k][d]), XOR-swizzled 128B rows
        int k = t >> 3, d8 = t & 7;
        const float* src = rp + (size_t)(pos + 31 - k) * 64 + d8 * 8;
        float4 f0 = *(const float4*)src;
        float4 f1 = *(const float4*)(src + 4);
        unsigned short hv[8] = { f2bf(f0.x), f2bf(f0.y), f2bf(f0.z), f2bf(f0.w),
                                 f2bf(f1.x), f2bf(f1.y), f2bf(f1.z), f2bf(f1.w) };
        int bo = k * 128 + ((d8 * 16) ^ ((k & 7) << 4));
        *(bf16x8*)((char*)Bs + bo) = *(bf16x8*)hv;
    }
    __syncthreads();
    bf16x8 bf[2][2];
#pragma unroll
    for (int s = 0; s < 2; ++s)
#pragma unroll
        for (int ks = 0; ks < 2; ++ks) {
            int row = s * 16 + C;
            int off = row * 128 + ((ks * 64 + G * 16) ^ ((row & 7) << 4));
            bf[s][ks] = *(const bf16x8*)((char*)Bs + off);
        }
#pragma unroll
    for (int ib = 0; ib < 4; ++ib) {
        int arow = ib * 64 + wid * 16 + C;
        int gi = arow >> 5, w = arow & 31;
        int hw = (mode == 0) ? (pos * 32 + w) : (w * 32 + pos);
        const unsigned short* qrow = qh + ((size_t)(g0 + gi) * 1024 + hw) * 64;
        bf16x8 a0 = *(const bf16x8*)(qrow + G * 8);
        bf16x8 a1 = *(const bf16x8*)(qrow + 32 + G * 8);
        f32x4 acc[2] = {};
#pragma unroll
        for (int s = 0; s < 2; ++s) {
            acc[s] = MFMA(a0, bf[s][0], acc[s]);
            acc[s] = MFMA(a1, bf[s][1], acc[s]);
        }
        unsigned short* dst = (mode == 0) ? relh : relw;
#pragma unroll
        for (int s = 0; s < 2; ++s)
#pragma unroll
            for (int rr = 0; rr < 4; ++rr) {
                int orow = ib * 64 + wid * 16 + 4 * G + rr;
                int ogi = orow >> 5, ow = orow & 31;
                int ohw = (mode == 0) ? (pos * 32 + ow) : (ow * 32 + pos);
                dst[((size_t)(g0 + ogi) * 1024 + ohw) * 32 + s * 16 + C] =
                    f2bf(acc[s][rr] * 8.0f);
            }
    }
}

// ---------------------------------------------------------------------------
// Flash attention, 4 waves x 16 q-rows + K-path 2-deep prefetch (Kh 3-ring,
// Vh dbuf). LDS 52.4KB -> 3 blocks/CU. In-order vmcnt schedule (all loads
// are global_load_lds -- single class): prologue K0,V0,K1; per iter issue
// V(kb+1), K(kb+2); steady vmcnt(6); kb=14 -> vmcnt(4); kb=15 -> vmcnt(0).
// ---------------------------------------------------------------------------
__global__ __launch_bounds__(256) void attn_mfma(
        const unsigned short* __restrict__ qh,
        const unsigned short* __restrict__ kh_g,
        const unsigned short* __restrict__ vth_g,
        const unsigned short* __restrict__ relh, const unsigned short* __restrict__ relw,
        unsigned short* __restrict__ atth) {
    __shared__ unsigned short Kh[3][4096], Vh[2][4096];
    __shared__ unsigned short Pl[4][1024];
    __shared__ unsigned short RelU[4][16 * 34];
    const int t = threadIdx.x;
    const int lane = t & 63, wid = t >> 6;
    const int C = lane & 15, G = lane >> 4;
    // XCD-aware swizzle: 768 blocks, 96 per XCD -> each XCD owns 6 whole heads
    const int bid = blockIdx.x;
    const int wgid = (bid & 7) * 96 + (bid >> 3);
    const int g = wgid >> 4, qb = wgid & 15;
    const int qtile = qb * 64 + wid * 16;

    // ---- stage rel_h rows (64 x 32 bf16) into per-wave LDS ----
    {
        const unsigned short* src = relh + ((size_t)g * 1024 + qb * 64) * 32;
#pragma unroll
        for (int j = 0; j < 8; ++j) {
            int i = t + j * 256;
            int row = i >> 5, col = i & 31;
            RelU[row >> 4][(row & 15) * 34 + col] = src[i];
        }
    }
    // ---- staging source addresses (per-lane, pre-swizzled) ----
    const int cbyt = ((lane & 7) << 4) ^ ((lane >> 3) << 4);
    const char* khbase = (const char*)(kh_g + (size_t)g * 65536)
                         + (wid * 16 + (lane >> 3)) * 128 + cbyt;
    const char* vhbase = (const char*)(vth_g + (size_t)g * 65536)
                         + (wid * 16 + (lane >> 3)) * 2048 + cbyt;
    // ---- Q fragments (hoisted, hi only) ----
    bf16x8 qfh[2];
    {
        size_t qo = ((size_t)g * 1024 + qtile + C) * 64;
        qfh[0] = *(const bf16x8*)(qh + qo + G * 8);
        qfh[1] = *(const bf16x8*)(qh + qo + 32 + G * 8);
    }
    // ---- rel_w hoisted: rw8[e][r] = relw[q=qtile+C][e*16 + 4G + r] ----
    float rw8[2][4];
    {
        const unsigned short* rwp = relw + ((size_t)g * 1024 + qtile + C) * 32;
#pragma unroll
        for (int e = 0; e < 2; ++e)
#pragma unroll
            for (int r = 0; r < 4; ++r)
                rw8[e][r] = bf2f(rwp[e * 16 + 4 * G + r]);
    }
    f32x4 O[4] = {};
    float m_ = -1e30f, l_ = 0.f;
    unsigned short* Pw = Pl[wid];

    __syncthreads();   // rel writes visible; drains all prologue vmem
    // ---- prologue: K0, V0, K1 (issue order matters for vmcnt schedule) ----
    {
        char* dK0 = (char*)Kh[0] + wid * 2048;
        char* dV0 = (char*)Vh[0] + wid * 2048;
        char* dK1 = (char*)Kh[1] + wid * 2048;
        gload16(khbase, dK0);          gload16(khbase + 1024, dK0 + 1024);
        gload16(vhbase, dV0);          gload16(vhbase + 16384, dV0 + 1024);
        gload16(khbase + 8192, dK1);   gload16(khbase + 9216, dK1 + 1024);
    }

    for (int kb = 0; kb < 16; ++kb) {
        if (kb < 15) {   // V[kb+1] -> Vh[(kb+1)&1]
            const char* sV = vhbase + (kb + 1) * 128;
            char* dV = (char*)Vh[(kb + 1) & 1] + wid * 2048;
            gload16(sV, dV); gload16(sV + 16384, dV + 1024);
        }
        if (kb < 14) {   // K[kb+2] -> Kh[(kb+2)%3]
            const char* sK = khbase + (kb + 2) * 8192;
            char* dK = (char*)Kh[(kb + 2) % 3] + wid * 2048;
            gload16(sK, dK); gload16(sK + 1024, dK + 1024);
        }
        __builtin_amdgcn_sched_barrier(0);
        if (kb < 14)      { asm volatile("s_waitcnt vmcnt(6)" ::: "memory"); }
        else if (kb < 15) { asm volatile("s_waitcnt vmcnt(4)" ::: "memory"); }
        else              { asm volatile("s_waitcnt vmcnt(0)" ::: "memory"); }
        __builtin_amdgcn_s_barrier();
        __builtin_amdgcn_sched_barrier(0);
        const unsigned short* khbuf = Kh[kb % 3];
        const unsigned short* vhbuf = Vh[kb & 1];
        // ---- QK^T swapped, hi-only: S[s][r] = score(q=qtile+C, k=16s+4G+r) ----
        f32x4 S[4] = {};
        __builtin_amdgcn_s_setprio(1);
#pragma unroll
        for (int ks = 0; ks < 2; ++ks) {
#pragma unroll
            for (int s = 0; s < 4; ++s) {
                int row = s * 16 + C;
                int off = row * 128 + ((ks * 64 + G * 16) ^ ((row & 7) << 4));
                bf16x8 bh = *(const bf16x8*)((char*)khbuf + off);
                S[s] = MFMA(bh, qfh[ks], S[s]);
            }
        }
        __builtin_amdgcn_s_setprio(0);
        // ---- rel terms: rh from LDS (1 dword), rw hoisted ----
        {
            unsigned rp = *(const unsigned*)((const char*)&RelU[wid][0]
                                             + C * 68 + 4 * kb);
            float rh0 = bf2f((unsigned short)(rp & 0xFFFF));
            float rh1 = bf2f((unsigned short)(rp >> 16));
#pragma unroll
            for (int s = 0; s < 4; ++s) {
                float rh = (s < 2) ? rh0 : rh1;
#pragma unroll
                for (int r = 0; r < 4; ++r)
                    S[s][r] += rh + rw8[s & 1][r];
            }
        }
        // ---- online softmax (scalar state, exp2 domain, defer-max) ----
        float mt = fm3(fm3(fm3(S[0][0], S[0][1], S[0][2]),
                           fm3(S[0][3], S[1][0], S[1][1]),
                           fm3(S[1][2], S[1][3], S[2][0])),
                       fm3(S[2][1], S[2][2], S[2][3]),
                       fm3(S[3][0], S[3][1], S[3][2]));
        mt = fmaxf(mt, S[3][3]);
        mt = fmaxf(mt, __shfl_xor(mt, 16));
        mt = fmaxf(mt, __shfl_xor(mt, 32));
        if (__any(mt - m_ > 11.f)) {
            float mn = fmaxf(m_, mt);
            float corr = exp2fast(m_ - mn);
            m_ = mn;
            l_ *= corr;
            float cO[4];
#pragma unroll
            for (int r = 0; r < 4; ++r) cO[r] = __shfl(corr, 4 * G + r);
#pragma unroll
            for (int s = 0; s < 4; ++s)
#pragma unroll
                for (int r = 0; r < 4; ++r) O[s][r] *= cO[r];
        }
        float lt = 0.f;
#pragma unroll
        for (int s = 0; s < 4; ++s)
#pragma unroll
            for (int r = 0; r < 4; ++r) {
                S[s][r] = exp2fast(S[s][r] - m_);
                lt += S[s][r];
            }
        l_ += lt;
        // ---- P pack: cvt_pk pairs (k consecutive) + ds_write_b64 ----
#pragma unroll
        for (int s = 0; s < 4; ++s) {
            unsigned d0, d1;
            asm("v_cvt_pk_bf16_f32 %0, %1, %2" : "=v"(d0) : "v"(S[s][0]), "v"(S[s][1]));
            asm("v_cvt_pk_bf16_f32 %0, %1, %2" : "=v"(d1) : "v"(S[s][2]), "v"(S[s][3]));
            int bo = C * 128 + (((s * 16 + 4 * G) * 2) ^ ((C & 7) << 4));
            uint2 dv; dv.x = d0; dv.y = d1;
            *(uint2*)((char*)Pw + bo) = dv;
        }
        // ---- PV (V hi only) ----
        __builtin_amdgcn_s_setprio(1);
#pragma unroll
        for (int ks = 0; ks < 2; ++ks) {
            int aoff = C * 128 + ((ks * 64 + G * 16) ^ ((C & 7) << 4));
            bf16x8 pa = *(const bf16x8*)((char*)Pw + aoff);
#pragma unroll
            for (int s = 0; s < 4; ++s) {
                int vrow = s * 16 + C;
                int voff = vrow * 128 + ((ks * 64 + G * 16) ^ ((vrow & 7) << 4));
                bf16x8 vh = *(const bf16x8*)((char*)vhbuf + voff);
                O[s] = MFMA(pa, vh, O[s]);
            }
        }
        __builtin_amdgcn_s_setprio(0);
        __builtin_amdgcn_s_barrier();   // bare: fence buffer reuse (no drain)
    }
    // ---- epilogue: reduce l across G, transpose to O layout, write hi ----
    l_ += __shfl_xor(l_, 16);
    l_ += __shfl_xor(l_, 32);
    const int b = g / 6, head = g - b * 6;
#pragma unroll
    for (int r = 0; r < 4; ++r) {
        float inv = 1.0f / __shfl(l_, 4 * G + r);
        int token = qtile + 4 * G + r;
        size_t ob = ((size_t)b * 1024 + token) * 384 + head * 64;
#pragma unroll
        for (int s = 0; s < 4; ++s)
            atth[ob + s * 16 + C] = f2bf(O[s][r] * inv);
    }
}

// ---------------------------------------------------------------------------
// Output projection: [8192,384] @ [384,384] + bias -> fp32 out. Hi-only,
// 2-buffer counted-vmcnt dbuf (single-class), chunked XCD swizzle.
// ---------------------------------------------------------------------------
__global__ __launch_bounds__(256) void proj_gemm_mfma(
        const unsigned short* __restrict__ ah_g,
        const unsigned short* __restrict__ bth,
        const float* __restrict__ bias, float* __restrict__ out) {
    __shared__ unsigned short Ah[2][4096], Bh[2][4096];
    const int t = threadIdx.x;
    const int lane = t & 63, wid = t >> 6;
    const int C = lane & 15, G = lane >> 4;
    const int nbid = (blockIdx.x & 7) * 96 + (blockIdx.x >> 3);
    const int row0 = (nbid / 6) * 64, col0 = (nbid % 6) * 64;
    const int rl = wid * 16 + (lane >> 3);
    const int cbyt = ((lane & 7) << 4) ^ ((lane >> 3) << 4);
    const char* pAh = (const char*)ah_g + (size_t)(row0 + rl) * 768 + cbyt;
    const char* pBh = (const char*)bth + (size_t)(col0 + rl) * 768 + cbyt;
    const int dof = wid * 2048;
    gload16(pAh, (char*)Ah[0] + dof); gload16(pAh + 6144, (char*)Ah[0] + dof + 1024);
    gload16(pBh, (char*)Bh[0] + dof); gload16(pBh + 6144, (char*)Bh[0] + dof + 1024);
    int cur = 0;
    f32x4 acc[4] = {};
    for (int kb = 0; kb < 6; ++kb) {
        if (kb < 5) {
            const int o = (kb + 1) * 128;
            gload16(pAh + o, (char*)Ah[cur^1] + dof); gload16(pAh + o + 6144, (char*)Ah[cur^1] + dof + 1024);
            gload16(pBh + o, (char*)Bh[cur^1] + dof); gload16(pBh + o + 6144, (char*)Bh[cur^1] + dof + 1024);
            __builtin_amdgcn_sched_barrier(0);
            asm volatile("s_waitcnt vmcnt(4)" ::: "memory");
        } else {
            asm volatile("s_waitcnt vmcnt(0)" ::: "memory");
        }
        __builtin_amdgcn_s_barrier();
        __builtin_amdgcn_sched_barrier(0);
        const unsigned short* AhB = Ah[cur];
        const unsigned short* BhB = Bh[cur];
#pragma unroll
        for (int ks = 0; ks < 2; ++ks) {
            int arow = wid * 16 + C;
            int aoff = arow * 128 + ((ks * 64 + G * 16) ^ ((arow & 7) << 4));
            bf16x8 ah = *(const bf16x8*)((char*)AhB + aoff);
#pragma unroll
            for (int s = 0; s < 4; ++s) {
                int brow = s * 16 + C;
                int boff = brow * 128 + ((ks * 64 + G * 16) ^ ((brow & 7) << 4));
                bf16x8 bh = *(const bf16x8*)((char*)BhB + boff);
                acc[s] = MFMA(ah, bh, acc[s]);
            }
        }
        __builtin_amdgcn_s_barrier();
        cur ^= 1;
    }
#pragma unroll
    for (int s = 0; s < 4; ++s) {
        int n = col0 + s * 16 + C;
        float bv = bias[n];
#pragma unroll
        for (int r = 0; r < 4; ++r) {
            int m = row0 + wid * 16 + 4 * G + r;
            out[(size_t)m * 384 + n] = acc[s][r] + bv;
        }
    }
}

extern "C" void kernel_launch(void* const* d_in, const int* in_sizes, int n_in,
                              void* d_out, int out_size, void* d_ws, size_t ws_size,
                              hipStream_t stream) {
    const float* x      = (const float*)d_in[0];
    const float* qkv_w  = (const float*)d_in[1];
    const float* qkv_b  = (const float*)d_in[2];
    const float* proj_w = (const float*)d_in[3];
    const float* proj_b = (const float*)d_in[4];
    const float* rph    = (const float*)d_in[5];
    const float* rpw    = (const float*)d_in[6];
    char* ws = (char*)d_ws;

    unsigned short* QHI  = (unsigned short*)(ws + WS_QHI);
    unsigned short* KHI  = (unsigned short*)(ws + WS_KHI);
    unsigned short* VTHI = (unsigned short*)(ws + WS_VTHI);
    unsigned short* RELH = (unsigned short*)(ws + WS_RELH);
    unsigned short* RELW = (unsigned short*)(ws + WS_RELW);
    unsigned short* WTH  = (unsigned short*)(ws + WS_WTH);
    unsigned short* PWTH = (unsigned short*)(ws + WS_PWTH);
    unsigned short* XHI  = (unsigned short*)(ws + WS_XHI);
    unsigned short* ATTH = XHI;   // reuse (x consumed before attn writes)

    prep_fused<<<3216, 256, 0, stream>>>(x, qkv_w, proj_w, XHI, WTH, PWTH);
    qkv_gemm_mfma<<<2304, 256, 0, stream>>>(XHI, WTH, qkv_b, QHI, KHI, VTHI);
    rel_mfma<<<dim3(32, 6, 2), 256, 0, stream>>>(QHI, rph, rpw, RELH, RELW);
    attn_mfma<<<768, 256, 0, stream>>>(QHI, KHI, VTHI, RELH, RELW, ATTH);
    proj_gemm_mfma<<<768, 256, 0, stream>>>(ATTH, PWTH, proj_b, (float*)d_out);
}